// Round 11
// baseline (3030.984 us; speedup 1.0000x reference)
//
#include <hip/hip_runtime.h>

#define VD 128
#define HD 1024
#define BD 64
#define TD 256
#define NB 256

typedef __bf16 bf16;
typedef __bf16 bf16x8 __attribute__((ext_vector_type(8)));
typedef __bf16 bf16x4 __attribute__((ext_vector_type(4)));
typedef float f32x4 __attribute__((ext_vector_type(4)));

// ---- ws layout (byte offsets) ----
#define OFF_OUTS 0ull                           // bf16 [T]{tiled [H/32][B][32]} hB stream
#define OFF_XW   33554432ull                    // bf16 x: tiled per t in stream mode, linear in fallback
#define OFF_WA1  (OFF_XW  + 4194304ull)         // bf16 [4H][V]
#define OFF_WA2  (OFF_WA1 + 1048576ull)         // bf16 [4H][H]
#define OFF_WB1  (OFF_WA2 + 8388608ull)         // bf16 [4H][H]
#define OFF_WB2  (OFF_WB1 + 8388608ull)         // bf16 [4H][H]
#define OFF_WFC  (OFF_WB2 + 8388608ull)         // bf16 [V][H]
#define OFF_BUFA (OFF_WFC + 262144ull)          // stream: TILED hB-init | fallback: linear hA parity
#define OFF_BUFB (OFF_BUFA + 262144ull)         // fallback linear hB parity
#define OFF_CAF  (OFF_BUFB + 262144ull)         // fp32 [B][H]
#define OFF_CBF  (OFF_CAF + 262144ull)
#define OFF_HAST (OFF_CBF + 262144ull)          // bf16 [257]{tiled} hA stream
#define HAST_BYTES (257ull * BD * HD * 2ull)

// Tiled h/x layout per slot: [K/32][B][32] bf16 (group stride 2048 elems).
// R10 post-mortem: depth-4 av[4][4] window needs ~64 VGPR; bare
// __launch_bounds__(512) capped allocation at 60 -> compiler SERIALIZED the
// window (no added MLP, +overhead, 2708->2995us). LDS (136.7KB) already
// caps the CU at 8 waves = 2 waves/SIMD, so declaring (512, 2) raises the
// budget to 256 VGPR at zero occupancy cost -> window lives in registers.

// dynamic LDS layout (bytes): unchanged from R8/R9
#define SMEM_BYTES 136704

// barrier: unchanged from R8/R9 (spread slots + 64 flag copies), monotonic,
// zeroed by init_k, bounded spins.
#define BAR_WORDS 8192
#define SPIN_CAP (1 << 16)

struct Params {   // fallback phase_k (all linear)
  const bf16 *x, *WA1, *WA2, *WB1, *WB2;
  const float *bA1, *bA2, *bB1, *bB2;
  bf16 *bufA, *bufB, *outs;
  float *cA, *cB;
};

struct PParams {  // persistent stream kernel (h/x tiled)
  const bf16 *x, *WA1, *WA2, *WB1, *WB2;
  const float *bA1, *bA2, *bB1, *bB2;
  const bf16 *hBinit;   // initial hB, TILED
  bf16 *hAst, *outs;    // hA stream [257] tiled; outs = hB stream [256] tiled
  float *cA, *cB;
};

__device__ __forceinline__ bf16x8 ld8(const bf16* p) {
  return *reinterpret_cast<const bf16x8*>(p);
}
__device__ __forceinline__ float sigf(float x) { return 1.f / (1.f + __expf(-x)); }

// device-scope write-through bf16 store: L2 never holds kernel-dirty lines.
__device__ __forceinline__ void st_dev_bf16(bf16* p, float f) {
  unsigned v = (unsigned)__builtin_bit_cast(unsigned short, (bf16)f);
  asm volatile("global_store_short %0, %1, off sc0 sc1" :: "v"(p), "v"(v) : "memory");
}

// fp32 -> bf16 staging. x goes TILED per t when sm=1 (stream), linear else.
__global__ void conv_k(const float* x, const float* WA1, const float* WA2,
                       const float* WB1, const float* WB2, const float* Wfc,
                       char* ws, int sm) {
  const size_t g4 = (size_t)blockIdx.x * 256 + threadIdx.x;
  size_t i = g4 * 4;
  if (i < 2097152ull) {  // x: T*B*V fp32
    float4 v = *reinterpret_cast<const float4*>(x + i);
    bf16x4 o = { (bf16)v.x, (bf16)v.y, (bf16)v.z, (bf16)v.w };
    bf16* dst = (bf16*)(ws + OFF_XW);
    if (sm) {
      size_t t = i >> 13, r = i & 8191, b = r >> 7, vv = r & 127;
      *reinterpret_cast<bf16x4*>(dst + t * 8192 + ((vv >> 5) << 11) + (b << 5) + (vv & 31)) = o;
    } else {
      *reinterpret_cast<bf16x4*>(dst + i) = o;
    }
    return;
  }
  const float* src;
  bf16* dst;
  size_t off;
  if (i < 2621440ull)        { src = WA1; dst = (bf16*)(ws + OFF_WA1); off = i - 2097152ull; }
  else if (i < 6815744ull)   { src = WA2; dst = (bf16*)(ws + OFF_WA2); off = i - 2621440ull; }
  else if (i < 11010048ull)  { src = WB1; dst = (bf16*)(ws + OFF_WB1); off = i - 6815744ull; }
  else if (i < 15204352ull)  { src = WB2; dst = (bf16*)(ws + OFF_WB2); off = i - 11010048ull; }
  else if (i < 15335424ull)  { src = Wfc; dst = (bf16*)(ws + OFF_WFC); off = i - 15204352ull; }
  else return;
  float4 v = *reinterpret_cast<const float4*>(src + off);
  bf16x4 o = { (bf16)v.x, (bf16)v.y, (bf16)v.z, (bf16)v.w };
  *reinterpret_cast<bf16x4*>(dst + off) = o;
}

__global__ void init_k(const float* hA, const float* cA, const float* hB, const float* cB,
                       char* ws, unsigned* bar, int sm) {
  int i = blockIdx.x * 256 + threadIdx.x;  // 65536 = B*H, i = b*1024 + j
  if (i < BAR_WORDS) bar[i] = 0u;          // reset flags+slots each replay
  ((float*)(ws + OFF_CAF))[i] = cA[i];
  ((float*)(ws + OFF_CBF))[i] = cB[i];
  ((bf16*)(ws + OFF_BUFB))[i] = (bf16)hB[i];   // fallback linear
  if (sm) {
    int b = i >> 10, j = i & 1023;
    int tix = ((j >> 5) << 11) + (b << 5) + (j & 31);
    ((bf16*)(ws + OFF_HAST))[tix] = (bf16)hA[i];  // hA stream slot 0, tiled
    ((bf16*)(ws + OFF_BUFA))[tix] = (bf16)hB[i];  // tiled hB-init (BUFA reused)
  } else {
    ((bf16*)(ws + OFF_BUFA))[i] = (bf16)hA[i];    // fallback linear parity-0
  }
}

// ---------------------------------------------------------------------------
// Persistent kernel (R10 structure + VGPR unlock via launch_bounds(512,2)):
// 256 blocks x 512 thr, 136.7 KB LDS -> 1 block/CU, all co-resident.
// Phase t: A-step t (t<T) + B-step t-1 (t>=1).
// Stream protocol (verified R5-R9): fresh-address tiled h per phase,
// write-through sc0sc1 stores, NO fences; spread slot/flag barrier.
// K-loops use a rolling av[4][4] register window (~16 loads/wave in flight).
// ONLY change vs R10: __launch_bounds__(512, 2) -> 256-VGPR budget so the
// window actually allocates (R10: capped at 60, window serialized).
// ---------------------------------------------------------------------------
__global__ void __launch_bounds__(512, 2) persist_k(PParams p, unsigned* bar) {
  extern __shared__ char smem[];
  float (*part)[16][65] = (float (*)[16][65])smem;
  bf16* sWA1 = (bf16*)(smem + 33280);
  bf16* sWA2 = (bf16*)(smem + 37632);
  bf16* sWB1 = (bf16*)(smem + 70656);
  bf16* sWB2 = (bf16*)(smem + 103680);

  const int tid = threadIdx.x;
  const int wv = tid >> 6, lane = tid & 63;
  const int lrow = lane & 15, q = lane >> 4;
  const int j0 = blockIdx.x * 4;
  const int cs = wv >> 2, kq = wv & 3;

  // ---- stage this block's weight slices into LDS (once) ----
  for (int i = tid; i < 256; i += 512) {        // WA1: 16 rows x 16 chunks of 8
    int r = i >> 4, c8 = (i & 15) * 8;
    int gr = (r >> 2) * HD + j0 + (r & 3);
    *(bf16x8*)(sWA1 + r * 136 + c8) = ld8(p.WA1 + (size_t)gr * VD + c8);
  }
  for (int i = tid; i < 2048; i += 512) {       // 16 rows x 128 chunks of 8
    int r = i >> 7, c8 = (i & 127) * 8;
    int gr = (r >> 2) * HD + j0 + (r & 3);
    size_t go = (size_t)gr * HD + c8;
    *(bf16x8*)(sWA2 + r * 1032 + c8) = ld8(p.WA2 + go);
    *(bf16x8*)(sWB1 + r * 1032 + c8) = ld8(p.WB1 + go);
    *(bf16x8*)(sWB2 + r * 1032 + c8) = ld8(p.WB2 + go);
  }

  // per-thread LDS read bases (weights stay k-linear in LDS)
  const bf16* lw1 = sWA1 + lrow * 136 + q * 8;
  const bf16* lw2 = sWA2 + lrow * 1032 + q * 8;
  const bf16* lwp = ((kq < 2) ? sWB1 : sWB2) + lrow * 1032 + q * 8 + (kq & 1) * 512;
  const int g0 = ((kq == 0) ? 0 : kq * 288 - 128) >> 5;  // A-cell h start group

  // elementwise-stage constants; ejj in lane bits 0-1 => 8B-contiguous stores
  const int ejj = tid & 3;
  const int eb = (tid >> 2) & 63;
  const int ecs = tid >> 8;
  const int ej = j0 + ejj;
  const int eidx = eb * HD + ej;                                   // c: linear
  const int etix = ((ej >> 5) << 11) + (eb << 5) + (ej & 31);      // h: tiled
  const float* b1 = ecs ? p.bB1 : p.bA1;
  const float* b2 = ecs ? p.bB2 : p.bA2;
  float* ec = ecs ? p.cB : p.cA;
  const int wb = ecs * 4;
  float bsum[4];
#pragma unroll
  for (int g = 0; g < 4; g++) bsum[g] = b1[g * HD + ej] + b2[g * HD + ej];
  float creg = ec[eidx];   // c-state owned by this thread for the whole run

  const int mrow = lrow << 5;  // per-m A offset base: ((m*16+lrow)<<5) = m*512 + mrow

  __syncthreads();

  for (int t = 0; t <= TD; t++) {
    const bool active = (cs == 0) ? (t < TD) : (t >= 1);
    const bf16* hA = p.hAst + (size_t)t * 65536;  // tiled slot t
    if (active) {
      f32x4 acc[4] = {};
      bf16x8 av[4][4];
      if (cs == 0) {
        // 9 uniform slots/wave: kq0 = 4 x + 5 h (groups 0..4); kq1-3 = 9 h
        const bf16* hb0 = hA + q * 8;
        if (kq == 0) {
          const bf16* xb = p.x + (size_t)t * 8192 + q * 8;  // tiled x slot t
#pragma unroll
          for (int s = 0; s < 4; s++)
#pragma unroll
            for (int m = 0; m < 4; m++)
              av[s][m] = ld8(xb + s * 2048 + m * 512 + mrow);
#pragma unroll
          for (int s = 0; s < 9; s++) {
            bf16x8 bfv = (s < 4) ? *(const bf16x8*)(lw1 + s * 32)
                                 : *(const bf16x8*)(lw2 + (s - 4) * 32);
#pragma unroll
            for (int m = 0; m < 4; m++)
              acc[m] = __builtin_amdgcn_mfma_f32_16x16x32_bf16(av[s & 3][m], bfv, acc[m], 0, 0, 0);
            if (s + 4 < 9) {   // refill with h group s (groups 0..4)
#pragma unroll
              for (int m = 0; m < 4; m++)
                av[s & 3][m] = ld8(hb0 + (size_t)s * 2048 + m * 512 + mrow);
            }
          }
        } else {
#pragma unroll
          for (int s = 0; s < 4; s++)
#pragma unroll
            for (int m = 0; m < 4; m++)
              av[s][m] = ld8(hb0 + (size_t)(g0 + s) * 2048 + m * 512 + mrow);
#pragma unroll
          for (int s = 0; s < 9; s++) {
            bf16x8 bfv = *(const bf16x8*)(lw2 + ((g0 + s) << 5));
#pragma unroll
            for (int m = 0; m < 4; m++)
              acc[m] = __builtin_amdgcn_mfma_f32_16x16x32_bf16(av[s & 3][m], bfv, acc[m], 0, 0, 0);
            if (s + 4 < 9) {
#pragma unroll
              for (int m = 0; m < 4; m++)
                av[s & 3][m] = ld8(hb0 + (size_t)(g0 + s + 4) * 2048 + m * 512 + mrow);
            }
          }
        }
      } else {
        // K-chain 2048 = hA@WB1 (0..1023) + hB@WB2 (1024..2047); 16 slots
        const bf16* hBb = (t == 1) ? p.hBinit : p.outs + (size_t)(t - 2) * 65536;
        const bf16* hp = ((kq < 2) ? hA : hBb) + (size_t)(kq & 1) * 32768 + q * 8;
#pragma unroll
        for (int s = 0; s < 4; s++)
#pragma unroll
          for (int m = 0; m < 4; m++)
            av[s][m] = ld8(hp + (size_t)s * 2048 + m * 512 + mrow);
#pragma unroll
        for (int s = 0; s < 16; s++) {
          bf16x8 bfv = *(const bf16x8*)(lwp + s * 32);
#pragma unroll
          for (int m = 0; m < 4; m++)
            acc[m] = __builtin_amdgcn_mfma_f32_16x16x32_bf16(av[s & 3][m], bfv, acc[m], 0, 0, 0);
          if (s + 4 < 16) {
#pragma unroll
            for (int m = 0; m < 4; m++)
              av[s & 3][m] = ld8(hp + (size_t)(s + 4) * 2048 + m * 512 + mrow);
          }
        }
      }
      // D layout: col(N)=lane&15, row(M)=q*4+r  [m89-verified]
#pragma unroll
      for (int m = 0; m < 4; m++)
#pragma unroll
        for (int r = 0; r < 4; r++)
          part[wv][lrow][m * 16 + q * 4 + r] = acc[m][r];
    }
    __syncthreads();

    // elementwise: tid 0..255 -> cell A, 256..511 -> cell B
    const bool ew = (ecs == 0) ? (t < TD) : (t >= 1);
    if (ew) {
      float g4[4];
#pragma unroll
      for (int g = 0; g < 4; g++) {
        int n = g * 4 + ejj;
        g4[g] = bsum[g] + part[wb + 0][n][eb] + part[wb + 1][n][eb] +
                part[wb + 2][n][eb] + part[wb + 3][n][eb];
      }
      float cn = sigf(g4[1]) * creg + sigf(g4[0]) * tanhf(g4[2]);
      float hn = sigf(g4[3]) * tanhf(cn);
      creg = cn;
      if (ecs == 0) {
        st_dev_bf16(p.hAst + (size_t)(t + 1) * 65536 + etix, hn);   // slot t+1
      } else {
        st_dev_bf16(p.outs + (size_t)(t - 1) * 65536 + etix, hn);   // hB stream
      }
    }

    // ---- grid barrier (R8: spread slots + distributed flag copies) ----
    if (t < TD) {
      asm volatile("s_waitcnt vmcnt(0)" ::: "memory");  // h stores at coherence pt
      __syncthreads();
      const unsigned tgt = (unsigned)(t + 1);
      if (blockIdx.x == 0 && wv == 0) {
        if (lane == 0)
          __hip_atomic_store(&bar[1024], tgt, __ATOMIC_RELAXED, __HIP_MEMORY_SCOPE_AGENT);
        int sp = 0;
        for (;;) {
          unsigned a0 = __hip_atomic_load(&bar[1024 + (lane * 4 + 0) * 16], __ATOMIC_RELAXED, __HIP_MEMORY_SCOPE_AGENT);
          unsigned a1 = __hip_atomic_load(&bar[1024 + (lane * 4 + 1) * 16], __ATOMIC_RELAXED, __HIP_MEMORY_SCOPE_AGENT);
          unsigned a2 = __hip_atomic_load(&bar[1024 + (lane * 4 + 2) * 16], __ATOMIC_RELAXED, __HIP_MEMORY_SCOPE_AGENT);
          unsigned a3 = __hip_atomic_load(&bar[1024 + (lane * 4 + 3) * 16], __ATOMIC_RELAXED, __HIP_MEMORY_SCOPE_AGENT);
          if (__all(a0 >= tgt && a1 >= tgt && a2 >= tgt && a3 >= tgt)) break;
          __builtin_amdgcn_s_sleep(2);
          if (++sp > SPIN_CAP) break;  // degrade, never hang
        }
        __hip_atomic_store(&bar[lane * 16], tgt, __ATOMIC_RELAXED, __HIP_MEMORY_SCOPE_AGENT);
      } else if (tid == 0) {
        __hip_atomic_store(&bar[1024 + blockIdx.x * 16], tgt, __ATOMIC_RELAXED, __HIP_MEMORY_SCOPE_AGENT);
        int sp = 0;
        while (__hip_atomic_load(&bar[(blockIdx.x & 63) * 16], __ATOMIC_RELAXED, __HIP_MEMORY_SCOPE_AGENT) < tgt) {
          __builtin_amdgcn_s_sleep(2);
          if (++sp > SPIN_CAP) break;  // degrade, never hang
        }
      }
      __syncthreads();
    }
  }
  ec[eidx] = creg;  // final c state for tail_k (dispatch-end release flushes)
}

// Fallback single-phase kernel (all-linear; used only if ws too small).
__global__ void __launch_bounds__(512) phase_k(Params p, int t) {
  __shared__ float part[8][16][65];
  const int tid = threadIdx.x;
  const int wv = tid >> 6, lane = tid & 63;
  const int lrow = lane & 15, q = lane >> 4;
  const int j0 = blockIdx.x * 4;
  const int cs = wv >> 2, kq = wv & 3;
  const int gate = lrow >> 2, jj = lrow & 3;
  const int grow = gate * HD + j0 + jj;

  const bf16 *w1, *w2;
  if (cs == 0) { w1 = p.WA1 + grow * VD + q * 8; w2 = p.WA2 + (size_t)grow * HD + q * 8; }
  else         { w1 = p.WB1 + (size_t)grow * HD + q * 8; w2 = p.WB2 + (size_t)grow * HD + q * 8; }

  const bool active = (cs == 0) ? (t < TD) : (t >= 1);
  const bf16* hA = p.bufA + ((t & 1) ? (size_t)BD * HD : 0);
  if (active) {
    f32x4 acc[4] = {};
    if (cs == 0) {
      if (kq == 0) {
        const bf16* xb = p.x + (size_t)t * BD * VD + q * 8;
#pragma unroll
        for (int s = 0; s < 4; s++) {
          bf16x8 bfv = ld8(w1 + s * 32);
          const bf16* ap = xb + s * 32;
#pragma unroll
          for (int m = 0; m < 4; m++) {
            bf16x8 afv = ld8(ap + (m * 16 + lrow) * VD);
            acc[m] = __builtin_amdgcn_mfma_f32_16x16x32_bf16(afv, bfv, acc[m], 0, 0, 0);
          }
        }
      }
      const int hk0 = (kq == 0) ? 0 : kq * 288 - 128;
      const int nh = (kq == 0) ? 5 : 9;
#pragma unroll 3
      for (int s = 0; s < nh; s++) {
        int hk = hk0 + s * 32;
        bf16x8 bfv = ld8(w2 + hk);
        const bf16* ap = hA + hk + q * 8;
#pragma unroll
        for (int m = 0; m < 4; m++) {
          bf16x8 afv = ld8(ap + (size_t)(m * 16 + lrow) * HD);
          acc[m] = __builtin_amdgcn_mfma_f32_16x16x32_bf16(afv, bfv, acc[m], 0, 0, 0);
        }
      }
    } else {
      const bf16* hB = p.bufB + (((t - 1) & 1) ? (size_t)BD * HD : 0);
      const bf16* hp = (kq < 2) ? hA : hB;
      const bf16* wp = (kq < 2) ? w1 : w2;
      const int k0 = (kq & 1) * 512;
#pragma unroll 4
      for (int s = 0; s < 16; s++) {
        int hk = k0 + s * 32;
        bf16x8 bfv = ld8(wp + hk);
        const bf16* ap = hp + hk + q * 8;
#pragma unroll
        for (int m = 0; m < 4; m++) {
          bf16x8 afv = ld8(ap + (size_t)(m * 16 + lrow) * HD);
          acc[m] = __builtin_amdgcn_mfma_f32_16x16x32_bf16(afv, bfv, acc[m], 0, 0, 0);
        }
      }
    }
#pragma unroll
    for (int m = 0; m < 4; m++)
#pragma unroll
      for (int r = 0; r < 4; r++)
        part[wv][lrow][m * 16 + q * 4 + r] = acc[m][r];
  }
  __syncthreads();

  const int eb = tid & 63;
  const int ejj = (tid >> 6) & 3;
  const int ecs = tid >> 8;
  const int ej = j0 + ejj;
  const int eidx = eb * HD + ej;
  const bool ew = (ecs == 0) ? (t < TD) : (t >= 1);
  if (ew) {
    const float* b1 = ecs ? p.bB1 : p.bA1;
    const float* b2 = ecs ? p.bB2 : p.bA2;
    float* ec = ecs ? p.cB : p.cA;
    const int wb = ecs * 4;
    float g4[4];
#pragma unroll
    for (int g = 0; g < 4; g++) {
      int n = g * 4 + ejj;
      g4[g] = b1[g * HD + ej] + b2[g * HD + ej] + part[wb + 0][n][eb] +
              part[wb + 1][n][eb] + part[wb + 2][n][eb] + part[wb + 3][n][eb];
    }
    float cold = ec[eidx];
    float cn = sigf(g4[1]) * cold + sigf(g4[0]) * tanhf(g4[2]);
    float hn = sigf(g4[3]) * tanhf(cn);
    ec[eidx] = cn;
    if (ecs == 0) {
      p.bufA[(((t + 1) & 1) ? (size_t)BD * HD : 0) + eidx] = (bf16)hn;
    } else {
      p.bufB[((t & 1) ? (size_t)BD * HD : 0) + eidx] = (bf16)hn;
      p.outs[((size_t)(t - 1) * BD + eb) * HD + ej] = (bf16)hn;
    }
  }
}

// out[T*B, V] = outs[T*B, H] @ Wfc[V, H]^T + bfc.  OUTPUT IS FP32.
// sm=1: outs is tiled per slot; row (t*64+b) -> slot t, batch b.
__global__ void fc_k(const bf16* outs, const bf16* Wfc, const float* bfc, float* out,
                     int sm) {
  const int tid = threadIdx.x;
  const int wv = tid >> 6, lane = tid & 63;
  const int lrow = lane & 15, q = lane >> 4;
  const int row0 = blockIdx.x * 64 + wv * 16;
  const bf16* arow;
  int astride;
  if (sm) {
    const int bb = wv * 16 + lrow;   // batch (block covers one t = blockIdx.x)
    arow = outs + (size_t)blockIdx.x * 65536 + (bb << 5) + q * 8;
    astride = 2048;
  } else {
    arow = outs + (size_t)(row0 + lrow) * HD + q * 8;
    astride = 32;
  }
  const bf16* wrow[8];
#pragma unroll
  for (int ct = 0; ct < 8; ct++) wrow[ct] = Wfc + (size_t)(ct * 16 + lrow) * HD + q * 8;
  f32x4 acc[8] = {};
#pragma unroll 2
  for (int s = 0; s < 32; s++) {
    bf16x8 afv = ld8(arow + (size_t)s * astride);
#pragma unroll
    for (int ct = 0; ct < 8; ct++) {
      bf16x8 bfv = ld8(wrow[ct] + s * 32);
      acc[ct] = __builtin_amdgcn_mfma_f32_16x16x32_bf16(afv, bfv, acc[ct], 0, 0, 0);
    }
  }
#pragma unroll
  for (int ct = 0; ct < 8; ct++) {
    float bv = bfc[ct * 16 + lrow];
#pragma unroll
    for (int r = 0; r < 4; r++)
      out[(size_t)(row0 + q * 4 + r) * VD + ct * 16 + lrow] = acc[ct][r] + bv;
  }
}

// final states: (hA, cA, hB, cB) appended after out[T*B,V], FP32.
__global__ void tail_k(const char* ws, float* out, int sm) {
  int i = blockIdx.x * 256 + threadIdx.x;  // 65536, i = b*1024 + j
  float* o = out + (size_t)TD * BD * VD;
  float hAv, hBv;
  if (sm) {
    int b = i >> 10, j = i & 1023;
    int tix = ((j >> 5) << 11) + (b << 5) + (j & 31);
    hAv = (float)(((const bf16*)(ws + OFF_HAST))[(size_t)TD * 65536 + tix]);
    hBv = (float)(((const bf16*)(ws + OFF_OUTS))[(size_t)(TD - 1) * 65536 + tix]);
  } else {
    hAv = (float)((const bf16*)(ws + OFF_BUFA))[i];
    hBv = (float)((const bf16*)(ws + OFF_BUFB))[i];
  }
  o[i]             = hAv;
  o[65536 + i]     = ((const float*)(ws + OFF_CAF))[i];
  o[2 * 65536 + i] = hBv;
  o[3 * 65536 + i] = ((const float*)(ws + OFF_CBF))[i];
}

extern "C" void kernel_launch(void* const* d_in, const int* in_sizes, int n_in,
                              void* d_out, int out_size, void* d_ws, size_t ws_size,
                              hipStream_t stream) {
  const float* x   = (const float*)d_in[0];
  const float* hA  = (const float*)d_in[1];
  const float* cA  = (const float*)d_in[2];
  const float* hB  = (const float*)d_in[3];
  const float* cB  = (const float*)d_in[4];
  const float* WA1 = (const float*)d_in[5];
  const float* bA1 = (const float*)d_in[6];
  const float* WA2 = (const float*)d_in[7];
  const float* bA2 = (const float*)d_in[8];
  const float* WB1 = (const float*)d_in[9];
  const float* bB1 = (const float*)d_in[10];
  const float* WB2 = (const float*)d_in[11];
  const float* bB2 = (const float*)d_in[12];
  const float* Wfc = (const float*)d_in[13];
  const float* bfc = (const float*)d_in[14];

  char* ws = (char*)d_ws;
  unsigned* bar = (unsigned*)d_out;  // scratch until fc_k overwrites it

  const int sm = (ws_size >= OFF_HAST + HAST_BYTES) ? 1 : 0;

  // allow >64 KB dynamic LDS for persist_k (host-side config, once)
  static bool attr_done = false;
  if (!attr_done) {
    hipFuncSetAttribute((const void*)persist_k,
                        hipFuncAttributeMaxDynamicSharedMemorySize, SMEM_BYTES);
    attr_done = true;
  }

  conv_k<<<(15335424 / 4 + 255) / 256, 256, 0, stream>>>(x, WA1, WA2, WB1, WB2, Wfc, ws, sm);
  init_k<<<256, 256, 0, stream>>>(hA, cA, hB, cB, ws, bar, sm);

  bool used_stream = false;
  if (sm) {
    PParams pp{(const bf16*)(ws + OFF_XW), (const bf16*)(ws + OFF_WA1),
               (const bf16*)(ws + OFF_WA2), (const bf16*)(ws + OFF_WB1),
               (const bf16*)(ws + OFF_WB2),
               bA1, bA2, bB1, bB2,
               (const bf16*)(ws + OFF_BUFA),           // tiled hB init
               (bf16*)(ws + OFF_HAST), (bf16*)(ws + OFF_OUTS),
               (float*)(ws + OFF_CAF), (float*)(ws + OFF_CBF)};
    persist_k<<<NB, 512, SMEM_BYTES, stream>>>(pp, bar);
    used_stream = (hipGetLastError() == hipSuccess);
  }
  if (!used_stream) {
    Params p{(const bf16*)(ws + OFF_XW), (const bf16*)(ws + OFF_WA1),
             (const bf16*)(ws + OFF_WA2), (const bf16*)(ws + OFF_WB1),
             (const bf16*)(ws + OFF_WB2),
             bA1, bA2, bB1, bB2,
             (bf16*)(ws + OFF_BUFA), (bf16*)(ws + OFF_BUFB), (bf16*)(ws + OFF_OUTS),
             (float*)(ws + OFF_CAF), (float*)(ws + OFF_CBF)};
    for (int t = 0; t <= TD; t++) {
      phase_k<<<NB, 512, 0, stream>>>(p, t);
    }
  }

  fc_k<<<256, 256, 0, stream>>>((const bf16*)(ws + OFF_OUTS), (const bf16*)(ws + OFF_WFC),
                                bfc, (float*)d_out, used_stream ? 1 : 0);
  tail_k<<<256, 256, 0, stream>>>(ws, (float*)d_out, used_stream ? 1 : 0);
}

// Round 12
// 2122.980 us; speedup vs baseline: 1.4277x; 1.4277x over previous
//
#include <hip/hip_runtime.h>

#define VD 128
#define HD 1024
#define BD 64
#define TD 256
#define NB 256

typedef __bf16 bf16;
typedef __bf16 bf16x8 __attribute__((ext_vector_type(8)));
typedef __bf16 bf16x4 __attribute__((ext_vector_type(4)));
typedef float f32x4 __attribute__((ext_vector_type(4)));

// ---- ws layout (byte offsets) ----
#define OFF_OUTS 0ull                           // bf16 [T]{tiled [H/32][B][32]} hB stream
#define OFF_XW   33554432ull                    // bf16 x: tiled per t in stream mode, linear in fallback
#define OFF_WA1  (OFF_XW  + 4194304ull)         // bf16 [4H][V]
#define OFF_WA2  (OFF_WA1 + 1048576ull)         // bf16 [4H][H]
#define OFF_WB1  (OFF_WA2 + 8388608ull)         // bf16 [4H][H]
#define OFF_WB2  (OFF_WB1 + 8388608ull)         // bf16 [4H][H]
#define OFF_WFC  (OFF_WB2 + 8388608ull)         // bf16 [V][H]
#define OFF_BUFA (OFF_WFC + 262144ull)          // stream: TILED hB-init | fallback: linear hA parity
#define OFF_BUFB (OFF_BUFA + 262144ull)         // fallback linear hB parity
#define OFF_CAF  (OFF_BUFB + 262144ull)         // fp32 [B][H]
#define OFF_CBF  (OFF_CAF + 262144ull)
#define OFF_HAST (OFF_CBF + 262144ull)          // bf16 [257]{tiled} hA stream
#define HAST_BYTES (257ull * BD * HD * 2ull)

// Tiled h/x layout per slot: [K/32][B][32] bf16 (group stride 2048 elems).
// R11 post-mortem: av-window dead (compiler sinks loads to uses; VGPR stayed
// 60 with (512,2) budget) -> K-loops reverted to R9 direct-load form.
// R12 change: wave w owns ONE K-eighth of hA (groups 4w..4w+3) and computes
// BOTH products from the same A-operand regs (accA += hA.WA2, accB += hA.WB1)
// -> hA read ONCE per block (400->272 KB/phase). Weight slices are now
// wave-private -> live in VGPRs (13 bf16x8/lane, prologue-loaded once);
// hot loop has ZERO ds_reads. LDS = part[2][8][16][65] only (66.5 KB; 87 KB
// requested keeps 1 block/CU co-residency).

// dynamic LDS request (bytes): > 80 KB so 2 blocks never share a CU
#define SMEM_BYTES 87040

// barrier: unchanged from R8/R9 (spread slots + 64 flag copies), monotonic,
// zeroed by init_k, bounded spins.
#define BAR_WORDS 8192
#define SPIN_CAP (1 << 16)

struct Params {   // fallback phase_k (all linear)
  const bf16 *x, *WA1, *WA2, *WB1, *WB2;
  const float *bA1, *bA2, *bB1, *bB2;
  bf16 *bufA, *bufB, *outs;
  float *cA, *cB;
};

struct PParams {  // persistent stream kernel (h/x tiled)
  const bf16 *x, *WA1, *WA2, *WB1, *WB2;
  const float *bA1, *bA2, *bB1, *bB2;
  const bf16 *hBinit;   // initial hB, TILED
  bf16 *hAst, *outs;    // hA stream [257] tiled; outs = hB stream [256] tiled
  float *cA, *cB;
};

__device__ __forceinline__ bf16x8 ld8(const bf16* p) {
  return *reinterpret_cast<const bf16x8*>(p);
}
__device__ __forceinline__ float sigf(float x) { return 1.f / (1.f + __expf(-x)); }

// device-scope write-through bf16 store: L2 never holds kernel-dirty lines.
__device__ __forceinline__ void st_dev_bf16(bf16* p, float f) {
  unsigned v = (unsigned)__builtin_bit_cast(unsigned short, (bf16)f);
  asm volatile("global_store_short %0, %1, off sc0 sc1" :: "v"(p), "v"(v) : "memory");
}

// fp32 -> bf16 staging. x goes TILED per t when sm=1 (stream), linear else.
__global__ void conv_k(const float* x, const float* WA1, const float* WA2,
                       const float* WB1, const float* WB2, const float* Wfc,
                       char* ws, int sm) {
  const size_t g4 = (size_t)blockIdx.x * 256 + threadIdx.x;
  size_t i = g4 * 4;
  if (i < 2097152ull) {  // x: T*B*V fp32
    float4 v = *reinterpret_cast<const float4*>(x + i);
    bf16x4 o = { (bf16)v.x, (bf16)v.y, (bf16)v.z, (bf16)v.w };
    bf16* dst = (bf16*)(ws + OFF_XW);
    if (sm) {
      size_t t = i >> 13, r = i & 8191, b = r >> 7, vv = r & 127;
      *reinterpret_cast<bf16x4*>(dst + t * 8192 + ((vv >> 5) << 11) + (b << 5) + (vv & 31)) = o;
    } else {
      *reinterpret_cast<bf16x4*>(dst + i) = o;
    }
    return;
  }
  const float* src;
  bf16* dst;
  size_t off;
  if (i < 2621440ull)        { src = WA1; dst = (bf16*)(ws + OFF_WA1); off = i - 2097152ull; }
  else if (i < 6815744ull)   { src = WA2; dst = (bf16*)(ws + OFF_WA2); off = i - 2621440ull; }
  else if (i < 11010048ull)  { src = WB1; dst = (bf16*)(ws + OFF_WB1); off = i - 6815744ull; }
  else if (i < 15204352ull)  { src = WB2; dst = (bf16*)(ws + OFF_WB2); off = i - 11010048ull; }
  else if (i < 15335424ull)  { src = Wfc; dst = (bf16*)(ws + OFF_WFC); off = i - 15204352ull; }
  else return;
  float4 v = *reinterpret_cast<const float4*>(src + off);
  bf16x4 o = { (bf16)v.x, (bf16)v.y, (bf16)v.z, (bf16)v.w };
  *reinterpret_cast<bf16x4*>(dst + off) = o;
}

__global__ void init_k(const float* hA, const float* cA, const float* hB, const float* cB,
                       char* ws, unsigned* bar, int sm) {
  int i = blockIdx.x * 256 + threadIdx.x;  // 65536 = B*H, i = b*1024 + j
  if (i < BAR_WORDS) bar[i] = 0u;          // reset flags+slots each replay
  ((float*)(ws + OFF_CAF))[i] = cA[i];
  ((float*)(ws + OFF_CBF))[i] = cB[i];
  ((bf16*)(ws + OFF_BUFB))[i] = (bf16)hB[i];   // fallback linear
  if (sm) {
    int b = i >> 10, j = i & 1023;
    int tix = ((j >> 5) << 11) + (b << 5) + (j & 31);
    ((bf16*)(ws + OFF_HAST))[tix] = (bf16)hA[i];  // hA stream slot 0, tiled
    ((bf16*)(ws + OFF_BUFA))[tix] = (bf16)hB[i];  // tiled hB-init (BUFA reused)
  } else {
    ((bf16*)(ws + OFF_BUFA))[i] = (bf16)hA[i];    // fallback linear parity-0
  }
}

// ---------------------------------------------------------------------------
// Persistent kernel v5 (hA-dedup + weights-in-VGPR):
// 256 blocks x 512 thr; LDS request 87 KB -> 1 block/CU, all co-resident.
// Phase t: A-step t (t<T) + B-step t-1 (t>=1).
// Wave w (0..7) owns K-eighth [128w,128w+128) as 4 groups of 32:
//   hA groups -> accA (x WA2, if t<TD) AND accB (x WB1, if t>=1)  [dedup]
//   hB groups -> accB (x WB2, t>=1); x group w (waves 0-3) -> accA (x WA1)
// Per-wave weight frags (13 bf16x8/lane) loaded ONCE into VGPRs in the
// prologue -> hot loop has no ds_read. part[cell][wave][16][65] in LDS.
// Stream protocol (verified R5-R9): fresh-address tiled h per phase,
// write-through sc0sc1 stores, NO fences; spread slot/flag barrier.
// ---------------------------------------------------------------------------
__global__ void __launch_bounds__(512, 2) persist_k(PParams p, unsigned* bar) {
  extern __shared__ char smem[];
  float (*part)[8][16][65] = (float (*)[8][16][65])smem;  // [cell][wave][lrow][col]

  const int tid = threadIdx.x;
  const int wv = tid >> 6, lane = tid & 63;
  const int lrow = lane & 15, q = lane >> 4;
  const int j0 = blockIdx.x * 4;
  const int grow = (lrow >> 2) * HD + j0 + (lrow & 3);  // gate-row for B-operand
  const int mrow = lrow << 5;                           // A-operand per-m base
  const int kbase = wv * 128;                           // wave's k-range start

  // ---- prologue: this wave's weight fragments -> VGPRs (once) ----
  bf16x8 wa2[4], wb1[4], wb2[4], wa1 = {};
#pragma unroll
  for (int g = 0; g < 4; g++) {
    const size_t ko = (size_t)grow * HD + kbase + g * 32 + q * 8;
    wa2[g] = ld8(p.WA2 + ko);
    wb1[g] = ld8(p.WB1 + ko);
    wb2[g] = ld8(p.WB2 + ko);
  }
  if (wv < 4) wa1 = ld8(p.WA1 + (size_t)grow * VD + wv * 32 + q * 8);

  // elementwise-stage constants; ejj in lane bits 0-1 => 8B-contiguous stores
  const int ejj = tid & 3;
  const int eb = (tid >> 2) & 63;
  const int ecs = tid >> 8;
  const int ej = j0 + ejj;
  const int eidx = eb * HD + ej;                                   // c: linear
  const int etix = ((ej >> 5) << 11) + (eb << 5) + (ej & 31);      // h: tiled
  const float* b1 = ecs ? p.bB1 : p.bA1;
  const float* b2 = ecs ? p.bB2 : p.bA2;
  float* ec = ecs ? p.cB : p.cA;
  float bsum[4];
#pragma unroll
  for (int g = 0; g < 4; g++) bsum[g] = b1[g * HD + ej] + b2[g * HD + ej];
  float creg = ec[eidx];   // c-state owned by this thread for the whole run

  __syncthreads();

  for (int t = 0; t <= TD; t++) {
    const bool doA = (t < TD), doB = (t >= 1);
    const bf16* hA = p.hAst + (size_t)t * 65536;      // tiled slot t
    const bf16* hAg = hA + wv * 8192 + q * 8;         // wave's hA k-base
    f32x4 accA[4] = {};
    f32x4 accB[4] = {};
    bf16x8 af[4];
    // hA groups: single load feeds BOTH cells
#pragma unroll
    for (int g = 0; g < 4; g++) {
#pragma unroll
      for (int m = 0; m < 4; m++)
        af[m] = ld8(hAg + g * 2048 + m * 512 + mrow);
      if (doA)
#pragma unroll
        for (int m = 0; m < 4; m++)
          accA[m] = __builtin_amdgcn_mfma_f32_16x16x32_bf16(af[m], wa2[g], accA[m], 0, 0, 0);
      if (doB)
#pragma unroll
        for (int m = 0; m < 4; m++)
          accB[m] = __builtin_amdgcn_mfma_f32_16x16x32_bf16(af[m], wb1[g], accB[m], 0, 0, 0);
    }
    // x group (waves 0-3 only)
    if (doA && wv < 4) {
      const bf16* xb = p.x + (size_t)t * 8192 + wv * 2048 + q * 8;
#pragma unroll
      for (int m = 0; m < 4; m++) {
        bf16x8 xf = ld8(xb + m * 512 + mrow);
        accA[m] = __builtin_amdgcn_mfma_f32_16x16x32_bf16(xf, wa1, accA[m], 0, 0, 0);
      }
    }
    // hB groups
    if (doB) {
      const bf16* hBb = (t == 1) ? p.hBinit : p.outs + (size_t)(t - 2) * 65536;
      const bf16* hBg = hBb + wv * 8192 + q * 8;
#pragma unroll
      for (int g = 0; g < 4; g++) {
#pragma unroll
        for (int m = 0; m < 4; m++) {
          bf16x8 bf_ = ld8(hBg + g * 2048 + m * 512 + mrow);
          accB[m] = __builtin_amdgcn_mfma_f32_16x16x32_bf16(bf_, wb2[g], accB[m], 0, 0, 0);
        }
      }
    }
    // D layout: col(N)=lane&15, row(M)=q*4+r  [m89-verified]
    if (doA)
#pragma unroll
      for (int m = 0; m < 4; m++)
#pragma unroll
        for (int r = 0; r < 4; r++)
          part[0][wv][lrow][m * 16 + q * 4 + r] = accA[m][r];
    if (doB)
#pragma unroll
      for (int m = 0; m < 4; m++)
#pragma unroll
        for (int r = 0; r < 4; r++)
          part[1][wv][lrow][m * 16 + q * 4 + r] = accB[m][r];
    __syncthreads();

    // elementwise: tid 0..255 -> cell A, 256..511 -> cell B; sum 8 wave parts
    const bool ew = (ecs == 0) ? doA : doB;
    if (ew) {
      float g4[4];
#pragma unroll
      for (int g = 0; g < 4; g++) {
        int n = g * 4 + ejj;
        float s = 0.f;
#pragma unroll
        for (int w = 0; w < 8; w++) s += part[ecs][w][n][eb];
        g4[g] = bsum[g] + s;
      }
      float cn = sigf(g4[1]) * creg + sigf(g4[0]) * tanhf(g4[2]);
      float hn = sigf(g4[3]) * tanhf(cn);
      creg = cn;
      if (ecs == 0) {
        st_dev_bf16(p.hAst + (size_t)(t + 1) * 65536 + etix, hn);   // slot t+1
      } else {
        st_dev_bf16(p.outs + (size_t)(t - 1) * 65536 + etix, hn);   // hB stream
      }
    }

    // ---- grid barrier (R8: spread slots + distributed flag copies) ----
    if (t < TD) {
      asm volatile("s_waitcnt vmcnt(0)" ::: "memory");  // h stores at coherence pt
      __syncthreads();
      const unsigned tgt = (unsigned)(t + 1);
      if (blockIdx.x == 0 && wv == 0) {
        if (lane == 0)
          __hip_atomic_store(&bar[1024], tgt, __ATOMIC_RELAXED, __HIP_MEMORY_SCOPE_AGENT);
        int sp = 0;
        for (;;) {
          unsigned a0 = __hip_atomic_load(&bar[1024 + (lane * 4 + 0) * 16], __ATOMIC_RELAXED, __HIP_MEMORY_SCOPE_AGENT);
          unsigned a1 = __hip_atomic_load(&bar[1024 + (lane * 4 + 1) * 16], __ATOMIC_RELAXED, __HIP_MEMORY_SCOPE_AGENT);
          unsigned a2 = __hip_atomic_load(&bar[1024 + (lane * 4 + 2) * 16], __ATOMIC_RELAXED, __HIP_MEMORY_SCOPE_AGENT);
          unsigned a3 = __hip_atomic_load(&bar[1024 + (lane * 4 + 3) * 16], __ATOMIC_RELAXED, __HIP_MEMORY_SCOPE_AGENT);
          if (__all(a0 >= tgt && a1 >= tgt && a2 >= tgt && a3 >= tgt)) break;
          __builtin_amdgcn_s_sleep(2);
          if (++sp > SPIN_CAP) break;  // degrade, never hang
        }
        __hip_atomic_store(&bar[lane * 16], tgt, __ATOMIC_RELAXED, __HIP_MEMORY_SCOPE_AGENT);
      } else if (tid == 0) {
        __hip_atomic_store(&bar[1024 + blockIdx.x * 16], tgt, __ATOMIC_RELAXED, __HIP_MEMORY_SCOPE_AGENT);
        int sp = 0;
        while (__hip_atomic_load(&bar[(blockIdx.x & 63) * 16], __ATOMIC_RELAXED, __HIP_MEMORY_SCOPE_AGENT) < tgt) {
          __builtin_amdgcn_s_sleep(2);
          if (++sp > SPIN_CAP) break;  // degrade, never hang
        }
      }
      __syncthreads();
    }
  }
  ec[eidx] = creg;  // final c state for tail_k (dispatch-end release flushes)
}

// Fallback single-phase kernel (all-linear; used only if ws too small).
__global__ void __launch_bounds__(512) phase_k(Params p, int t) {
  __shared__ float part[8][16][65];
  const int tid = threadIdx.x;
  const int wv = tid >> 6, lane = tid & 63;
  const int lrow = lane & 15, q = lane >> 4;
  const int j0 = blockIdx.x * 4;
  const int cs = wv >> 2, kq = wv & 3;
  const int gate = lrow >> 2, jj = lrow & 3;
  const int grow = gate * HD + j0 + jj;

  const bf16 *w1, *w2;
  if (cs == 0) { w1 = p.WA1 + grow * VD + q * 8; w2 = p.WA2 + (size_t)grow * HD + q * 8; }
  else         { w1 = p.WB1 + (size_t)grow * HD + q * 8; w2 = p.WB2 + (size_t)grow * HD + q * 8; }

  const bool active = (cs == 0) ? (t < TD) : (t >= 1);
  const bf16* hA = p.bufA + ((t & 1) ? (size_t)BD * HD : 0);
  if (active) {
    f32x4 acc[4] = {};
    if (cs == 0) {
      if (kq == 0) {
        const bf16* xb = p.x + (size_t)t * BD * VD + q * 8;
#pragma unroll
        for (int s = 0; s < 4; s++) {
          bf16x8 bfv = ld8(w1 + s * 32);
          const bf16* ap = xb + s * 32;
#pragma unroll
          for (int m = 0; m < 4; m++) {
            bf16x8 afv = ld8(ap + (m * 16 + lrow) * VD);
            acc[m] = __builtin_amdgcn_mfma_f32_16x16x32_bf16(afv, bfv, acc[m], 0, 0, 0);
          }
        }
      }
      const int hk0 = (kq == 0) ? 0 : kq * 288 - 128;
      const int nh = (kq == 0) ? 5 : 9;
#pragma unroll 3
      for (int s = 0; s < nh; s++) {
        int hk = hk0 + s * 32;
        bf16x8 bfv = ld8(w2 + hk);
        const bf16* ap = hA + hk + q * 8;
#pragma unroll
        for (int m = 0; m < 4; m++) {
          bf16x8 afv = ld8(ap + (size_t)(m * 16 + lrow) * HD);
          acc[m] = __builtin_amdgcn_mfma_f32_16x16x32_bf16(afv, bfv, acc[m], 0, 0, 0);
        }
      }
    } else {
      const bf16* hB = p.bufB + (((t - 1) & 1) ? (size_t)BD * HD : 0);
      const bf16* hp = (kq < 2) ? hA : hB;
      const bf16* wp = (kq < 2) ? w1 : w2;
      const int k0 = (kq & 1) * 512;
#pragma unroll 4
      for (int s = 0; s < 16; s++) {
        int hk = k0 + s * 32;
        bf16x8 bfv = ld8(wp + hk);
        const bf16* ap = hp + hk + q * 8;
#pragma unroll
        for (int m = 0; m < 4; m++) {
          bf16x8 afv = ld8(ap + (size_t)(m * 16 + lrow) * HD);
          acc[m] = __builtin_amdgcn_mfma_f32_16x16x32_bf16(afv, bfv, acc[m], 0, 0, 0);
        }
      }
    }
#pragma unroll
    for (int m = 0; m < 4; m++)
#pragma unroll
      for (int r = 0; r < 4; r++)
        part[wv][lrow][m * 16 + q * 4 + r] = acc[m][r];
  }
  __syncthreads();

  const int eb = tid & 63;
  const int ejj = (tid >> 6) & 3;
  const int ecs = tid >> 8;
  const int ej = j0 + ejj;
  const int eidx = eb * HD + ej;
  const bool ew = (ecs == 0) ? (t < TD) : (t >= 1);
  if (ew) {
    const float* b1 = ecs ? p.bB1 : p.bA1;
    const float* b2 = ecs ? p.bB2 : p.bA2;
    float* ec = ecs ? p.cB : p.cA;
    const int wb = ecs * 4;
    float g4[4];
#pragma unroll
    for (int g = 0; g < 4; g++) {
      int n = g * 4 + ejj;
      g4[g] = b1[g * HD + ej] + b2[g * HD + ej] + part[wb + 0][n][eb] +
              part[wb + 1][n][eb] + part[wb + 2][n][eb] + part[wb + 3][n][eb];
    }
    float cold = ec[eidx];
    float cn = sigf(g4[1]) * cold + sigf(g4[0]) * tanhf(g4[2]);
    float hn = sigf(g4[3]) * tanhf(cn);
    ec[eidx] = cn;
    if (ecs == 0) {
      p.bufA[(((t + 1) & 1) ? (size_t)BD * HD : 0) + eidx] = (bf16)hn;
    } else {
      p.bufB[((t & 1) ? (size_t)BD * HD : 0) + eidx] = (bf16)hn;
      p.outs[((size_t)(t - 1) * BD + eb) * HD + ej] = (bf16)hn;
    }
  }
}

// out[T*B, V] = outs[T*B, H] @ Wfc[V, H]^T + bfc.  OUTPUT IS FP32.
// sm=1: outs is tiled per slot; row (t*64+b) -> slot t, batch b.
__global__ void fc_k(const bf16* outs, const bf16* Wfc, const float* bfc, float* out,
                     int sm) {
  const int tid = threadIdx.x;
  const int wv = tid >> 6, lane = tid & 63;
  const int lrow = lane & 15, q = lane >> 4;
  const int row0 = blockIdx.x * 64 + wv * 16;
  const bf16* arow;
  int astride;
  if (sm) {
    const int bb = wv * 16 + lrow;   // batch (block covers one t = blockIdx.x)
    arow = outs + (size_t)blockIdx.x * 65536 + (bb << 5) + q * 8;
    astride = 2048;
  } else {
    arow = outs + (size_t)(row0 + lrow) * HD + q * 8;
    astride = 32;
  }
  const bf16* wrow[8];
#pragma unroll
  for (int ct = 0; ct < 8; ct++) wrow[ct] = Wfc + (size_t)(ct * 16 + lrow) * HD + q * 8;
  f32x4 acc[8] = {};
#pragma unroll 2
  for (int s = 0; s < 32; s++) {
    bf16x8 afv = ld8(arow + (size_t)s * astride);
#pragma unroll
    for (int ct = 0; ct < 8; ct++) {
      bf16x8 bfv = ld8(wrow[ct] + s * 32);
      acc[ct] = __builtin_amdgcn_mfma_f32_16x16x32_bf16(afv, bfv, acc[ct], 0, 0, 0);
    }
  }
#pragma unroll
  for (int ct = 0; ct < 8; ct++) {
    float bv = bfc[ct * 16 + lrow];
#pragma unroll
    for (int r = 0; r < 4; r++)
      out[(size_t)(row0 + q * 4 + r) * VD + ct * 16 + lrow] = acc[ct][r] + bv;
  }
}

// final states: (hA, cA, hB, cB) appended after out[T*B,V], FP32.
__global__ void tail_k(const char* ws, float* out, int sm) {
  int i = blockIdx.x * 256 + threadIdx.x;  // 65536, i = b*1024 + j
  float* o = out + (size_t)TD * BD * VD;
  float hAv, hBv;
  if (sm) {
    int b = i >> 10, j = i & 1023;
    int tix = ((j >> 5) << 11) + (b << 5) + (j & 31);
    hAv = (float)(((const bf16*)(ws + OFF_HAST))[(size_t)TD * 65536 + tix]);
    hBv = (float)(((const bf16*)(ws + OFF_OUTS))[(size_t)(TD - 1) * 65536 + tix]);
  } else {
    hAv = (float)((const bf16*)(ws + OFF_BUFA))[i];
    hBv = (float)((const bf16*)(ws + OFF_BUFB))[i];
  }
  o[i]             = hAv;
  o[65536 + i]     = ((const float*)(ws + OFF_CAF))[i];
  o[2 * 65536 + i] = hBv;
  o[3 * 65536 + i] = ((const float*)(ws + OFF_CBF))[i];
}

extern "C" void kernel_launch(void* const* d_in, const int* in_sizes, int n_in,
                              void* d_out, int out_size, void* d_ws, size_t ws_size,
                              hipStream_t stream) {
  const float* x   = (const float*)d_in[0];
  const float* hA  = (const float*)d_in[1];
  const float* cA  = (const float*)d_in[2];
  const float* hB  = (const float*)d_in[3];
  const float* cB  = (const float*)d_in[4];
  const float* WA1 = (const float*)d_in[5];
  const float* bA1 = (const float*)d_in[6];
  const float* WA2 = (const float*)d_in[7];
  const float* bA2 = (const float*)d_in[8];
  const float* WB1 = (const float*)d_in[9];
  const float* bB1 = (const float*)d_in[10];
  const float* WB2 = (const float*)d_in[11];
  const float* bB2 = (const float*)d_in[12];
  const float* Wfc = (const float*)d_in[13];
  const float* bfc = (const float*)d_in[14];

  char* ws = (char*)d_ws;
  unsigned* bar = (unsigned*)d_out;  // scratch until fc_k overwrites it

  const int sm = (ws_size >= OFF_HAST + HAST_BYTES) ? 1 : 0;

  // allow >64 KB dynamic LDS for persist_k (host-side config, once)
  static bool attr_done = false;
  if (!attr_done) {
    hipFuncSetAttribute((const void*)persist_k,
                        hipFuncAttributeMaxDynamicSharedMemorySize, SMEM_BYTES);
    attr_done = true;
  }

  conv_k<<<(15335424 / 4 + 255) / 256, 256, 0, stream>>>(x, WA1, WA2, WB1, WB2, Wfc, ws, sm);
  init_k<<<256, 256, 0, stream>>>(hA, cA, hB, cB, ws, bar, sm);

  bool used_stream = false;
  if (sm) {
    PParams pp{(const bf16*)(ws + OFF_XW), (const bf16*)(ws + OFF_WA1),
               (const bf16*)(ws + OFF_WA2), (const bf16*)(ws + OFF_WB1),
               (const bf16*)(ws + OFF_WB2),
               bA1, bA2, bB1, bB2,
               (const bf16*)(ws + OFF_BUFA),           // tiled hB init
               (bf16*)(ws + OFF_HAST), (bf16*)(ws + OFF_OUTS),
               (float*)(ws + OFF_CAF), (float*)(ws + OFF_CBF)};
    persist_k<<<NB, 512, SMEM_BYTES, stream>>>(pp, bar);
    used_stream = (hipGetLastError() == hipSuccess);
  }
  if (!used_stream) {
    Params p{(const bf16*)(ws + OFF_XW), (const bf16*)(ws + OFF_WA1),
             (const bf16*)(ws + OFF_WA2), (const bf16*)(ws + OFF_WB1),
             (const bf16*)(ws + OFF_WB2),
             bA1, bA2, bB1, bB2,
             (bf16*)(ws + OFF_BUFA), (bf16*)(ws + OFF_BUFB), (bf16*)(ws + OFF_OUTS),
             (float*)(ws + OFF_CAF), (float*)(ws + OFF_CBF)};
    for (int t = 0; t <= TD; t++) {
      phase_k<<<NB, 512, 0, stream>>>(p, t);
    }
  }

  fc_k<<<256, 256, 0, stream>>>((const bf16*)(ws + OFF_OUTS), (const bf16*)(ws + OFF_WFC),
                                bfc, (float*)d_out, used_stream ? 1 : 0);
  tail_k<<<256, 256, 0, stream>>>(ws, (float*)d_out, used_stream ? 1 : 0);
}